// Round 5
// baseline (214.170 us; speedup 1.0000x reference)
//
#include <hip/hip_runtime.h>

// B=16, Q=2048, K=2048, D=128, DV=128
// out[b,q,:] = softmax_k((q.k - 0.5||k||^2)/sqrt(192), mask k>=valid_len) @ V
// R13: LDS-pipe relief. Pipe audit of R8/R12 (64us): 20 ds_read_b128/wave/iter
// + 64KB/CU DMA writes = ~2430 LDS-pipe cycles per 2400 available -> LDS 100%
// saturated; explains why all scheduling restructures (R9/R12) were neutral.
// Change: K fragments now loaded DIRECTLY global->registers (A-operand rows,
// one row/lane, L2-resident, lines fully consumed via L1), double-buffered
// one tile ahead (kfA/kfB). Only V + bias stay in LDS (DMA, counted vmcnt).
// LDS read traffic drops 20->12 b128/wave/iter, writes halve. vmcnt(13) =
// {8 K reg-loads + 5 V/bias DMAs} of the next tile stay in flight.

#define Bn   16
#define Qn   2048
#define Kn   2048
#define Dn   128
#define DVn  128
#define BQ   64
#define BK   64

// (1/sqrt(192)) * log2(e) : softmax computed as 2^(qk*SC2 + bias2)
#define SC2 0.10411754f

typedef short bf16x4 __attribute__((ext_vector_type(4)));
typedef short bf16x8 __attribute__((ext_vector_type(8)));
typedef float f32x16 __attribute__((ext_vector_type(16)));

__device__ __forceinline__ short f2bf(float x) {   // RNE
    union { float f; unsigned u; } v; v.f = x;
    unsigned r = (v.u + 0x7fffu + ((v.u >> 16) & 1u)) >> 16;
    return (short)r;
}

typedef const __attribute__((address_space(1))) void* gas_t;
typedef __attribute__((address_space(3))) void* las_t;
__device__ __forceinline__ void gld16(const void* g, void* l) {
    __builtin_amdgcn_global_load_lds((gas_t)g, (las_t)l, 16, 0, 0);
}
__device__ __forceinline__ void gld4(const void* g, void* l) {
    __builtin_amdgcn_global_load_lds((gas_t)g, (las_t)l, 4, 0, 0);
}
__device__ __forceinline__ float exp2_raw(float a) {  // D = 2^S0
    float p;
    asm("v_exp_f32 %0, %1" : "=v"(p) : "v"(a));
    return p;
}

// counted waits ("memory" clobber: compiler can't move loads across)
#define VMW13() asm volatile("s_waitcnt vmcnt(13)" ::: "memory")
#define VMW0()  asm volatile("s_waitcnt vmcnt(0)" ::: "memory")
#define LGW()   asm volatile("s_waitcnt lgkmcnt(0)" ::: "memory")

// ---------- preprocess (R11: coalesced) ----------
__global__ __launch_bounds__(256) void prep_kv(const float* __restrict__ Kg,
                                               const float* __restrict__ Vg,
                                               short* __restrict__ Kb,
                                               short* __restrict__ Vtb,
                                               float* __restrict__ biasg) {
    const int tid = threadIdx.x;
    if (blockIdx.x < 1024) {
        // ---- K path: 32 rows (b*Kn+row flat) per block, fully coalesced ----
        const int rowbase = blockIdx.x * 32;
        const float* src = Kg + (size_t)rowbase * Dn;
        short*       dst = Kb + (size_t)rowbase * Dn;
#pragma unroll
        for (int p = 0; p < 4; ++p) {
            const int idx = p * 1024 + tid * 4;     // flat float index
            float4 x = *(const float4*)(src + idx);
            bf16x4 h;
            h[0] = f2bf(x.x); h[1] = f2bf(x.y); h[2] = f2bf(x.z); h[3] = f2bf(x.w);
            *(bf16x4*)(dst + idx) = h;
            float ssq = x.x*x.x + x.y*x.y + x.z*x.z + x.w*x.w;
            ssq += __shfl_xor(ssq, 1);
            ssq += __shfl_xor(ssq, 2);
            ssq += __shfl_xor(ssq, 4);
            ssq += __shfl_xor(ssq, 8);
            ssq += __shfl_xor(ssq, 16);
            if ((tid & 31) == 0)
                biasg[rowbase + p * 8 + (tid >> 5)] = -0.5f * ssq * SC2;
        }
    } else {
        // ---- V path: transpose one [64 k][128 v] tile to plain V^T bf16 ----
        const int blk = blockIdx.x - 1024;
        const int b  = blk >> 5;
        const int k0 = (blk & 31) * 64;
        __shared__ short Ls[64 * 128];
        // phase 1: coalesced float4 row reads; XOR-swizzled LDS writes
#pragma unroll
        for (int p = 0; p < 8; ++p) {
            const int kk = p * 8 + (tid >> 5);      // tile row 0..63
            const int v0 = (tid & 31) * 4;
            float4 x = *(const float4*)(Vg + ((size_t)b * Kn + k0 + kk) * DVn + v0);
            bf16x4 h;
            h[0] = f2bf(x.x); h[1] = f2bf(x.y); h[2] = f2bf(x.z); h[3] = f2bf(x.w);
            const int vs = v0 ^ ((kk & 15) << 3);   // keeps 4-short alignment
            *(bf16x4*)&Ls[kk * 128 + vs] = h;
        }
        __syncthreads();
        // phase 2: column gather (32 scalar reads) + coalesced 64B stores
        const int v = tid >> 1;
        const int h = (tid & 1) * 32;
        short* dst = Vtb + ((size_t)b * DVn + v) * Kn + k0 + h;
#pragma unroll
        for (int j4 = 0; j4 < 4; ++j4) {
            bf16x8 o;
#pragma unroll
            for (int j = 0; j < 8; ++j) {
                const int kk = h + j4 * 8 + j;
                o[j] = Ls[kk * 128 + (v ^ ((kk & 15) << 3))];
            }
            *(bf16x8*)(dst + j4 * 8) = o;
        }
    }
}

// epilogue helpers with LITERAL accumulator indices (no runtime Oacc[] index)
#define DUMP_ACC(ACC, DST)                                            \
    {                                                                 \
        _Pragma("unroll")                                             \
        for (int reg = 0; reg < 16; ++reg) {                          \
            const int row = (reg & 3) + 8 * (reg >> 2) + 4 * hi;      \
            (DST)[row * 32 + l31] = (ACC)[reg];                       \
        }                                                             \
    }
#define STORE_ACC(ACC, SRC, COLBASE)                                  \
    {                                                                 \
        _Pragma("unroll")                                             \
        for (int reg = 0; reg < 16; ++reg) {                          \
            const int row = (reg & 3) + 8 * (reg >> 2) + 4 * hi;      \
            const float o = (ACC)[reg] + (SRC)[row * 32 + l31];       \
            obase[(size_t)row * DVn + (COLBASE) + l31] = o * invl[reg]; \
        }                                                             \
    }

// ---- R13 loop building blocks (all register indices literal) ----

// K fragments of tile T: direct global loads (plain rows; no swizzle)
#define KLOAD(T, DST)                                                      \
    {                                                                      \
        const short* kp = kptr + (size_t)(T) * (BK * Dn);                  \
        _Pragma("unroll")                                                  \
        for (int kt = 0; kt < 8; ++kt)                                     \
            DST[kt] = *(const bf16x8*)(kp + kt * 16);                      \
    }

// V frags + bias of tile I from LDS into registers
#define VFRAGS(I)                                                          \
    {                                                                      \
        const short* vbuf = Vsh[(I) & 1];                                  \
        _Pragma("unroll")                                                  \
        for (int kt = 0; kt < 2; ++kt) {                                   \
            const int kc = half * 4 + kt * 2 + hi;                         \
            _Pragma("unroll")                                              \
            for (int nt = 0; nt < 4; ++nt) {                               \
                const int v  = nt * 32 + l31;                              \
                const int r  = v >> 1;                                     \
                const int p  = ((v & 1) * 8 + kc) ^ (r & 15);              \
                vfr[kt][nt] = *(const bf16x8*)&vbuf[r * 128 + p * 8];      \
            }                                                              \
        }                                                                  \
        _Pragma("unroll")                                                  \
        for (int rq = 0; rq < 4; ++rq)                                     \
            bv[rq] = *(const float4*)&biasSh[(I) & 1][half * 32 + rq * 8 + hi * 4]; \
    }

// stage tile T's V + bias via DMA (5 vmem ops/wave; bias redundant per wave
// to keep per-wave vmem counts uniform for counted vmcnt)
#define STAGEV(T)                                                          \
    {                                                                      \
        const int nk = (T) * BK;                                           \
        _Pragma("unroll")                                                  \
        for (int u = 0; u < 4; ++u)                                        \
            gld16(vsp[u] + nk, &Vsh[(T) & 1][vdo[u]]);                     \
        gld4(bias_b + nk + lane, &biasSh[(T) & 1][0]);                     \
    }

// S + softmax + PV for tile I; K frags in KF, V frags in vfr, bias in bv
#define COMPUTE(I, KF)                                                     \
    {                                                                      \
        f32x16 Sv;                                                         \
        _Pragma("unroll")                                                  \
        for (int j = 0; j < 16; ++j) Sv[j] = 0.f;                          \
        __builtin_amdgcn_s_setprio(1);                                     \
        _Pragma("unroll")                                                  \
        for (int kt = 0; kt < 8; ++kt)                                     \
            Sv = __builtin_amdgcn_mfma_f32_32x32x16_bf16(KF[kt], qf[kt], Sv, 0, 0, 0); \
        __builtin_amdgcn_s_setprio(0);                                     \
        _Pragma("unroll")                                                  \
        for (int rq = 0; rq < 4; ++rq) {                                   \
            _Pragma("unroll")                                              \
            for (int r = 0; r < 4; ++r) {                                  \
                const int reg = rq * 4 + r;                                \
                const int keyg = (I) * BK + half * 32 + rq * 8 + hi * 4 + r; \
                float a = fmaf(Sv[reg], SC2, bv[rq][r]);                   \
                a = (keyg < vlq) ? a : -200.0f;                            \
                const float p = exp2_raw(a);                               \
                psum += p;                                                 \
                Sv[reg] = p;                                               \
            }                                                              \
        }                                                                  \
        _Pragma("unroll")                                                  \
        for (int kt = 0; kt < 2; ++kt) {                                   \
            unsigned kAx = __builtin_amdgcn_perm(__float_as_uint(Sv[(2*kt)*4+1]),   \
                                                 __float_as_uint(Sv[(2*kt)*4+0]), 0x07060302u); \
            unsigned kAy = __builtin_amdgcn_perm(__float_as_uint(Sv[(2*kt)*4+3]),   \
                                                 __float_as_uint(Sv[(2*kt)*4+2]), 0x07060302u); \
            unsigned kBx = __builtin_amdgcn_perm(__float_as_uint(Sv[(2*kt+1)*4+1]), \
                                                 __float_as_uint(Sv[(2*kt+1)*4+0]), 0x07060302u); \
            unsigned kBy = __builtin_amdgcn_perm(__float_as_uint(Sv[(2*kt+1)*4+3]), \
                                                 __float_as_uint(Sv[(2*kt+1)*4+2]), 0x07060302u); \
            const unsigned sx = hi ? kAx : kBx;                            \
            const unsigned sy = hi ? kAy : kBy;                            \
            const unsigned rx = __shfl_xor(sx, 32);                        \
            const unsigned ry = __shfl_xor(sy, 32);                        \
            uint4 au;                                                      \
            au.x = hi ? rx : kAx;                                          \
            au.y = hi ? ry : kAy;                                          \
            au.z = hi ? kBx : rx;                                          \
            au.w = hi ? kBy : ry;                                          \
            const bf16x8 af = __builtin_bit_cast(bf16x8, au);              \
            __builtin_amdgcn_s_setprio(1);                                 \
            Oacc[0] = __builtin_amdgcn_mfma_f32_32x32x16_bf16(af, vfr[kt][0], Oacc[0], 0, 0, 0); \
            Oacc[1] = __builtin_amdgcn_mfma_f32_32x32x16_bf16(af, vfr[kt][1], Oacc[1], 0, 0, 0); \
            Oacc[2] = __builtin_amdgcn_mfma_f32_32x32x16_bf16(af, vfr[kt][2], Oacc[2], 0, 0, 0); \
            Oacc[3] = __builtin_amdgcn_mfma_f32_32x32x16_bf16(af, vfr[kt][3], Oacc[3], 0, 0, 0); \
            __builtin_amdgcn_s_setprio(0);                                 \
        }                                                                  \
    }

// one iteration: issue K(I+1) reg-loads; wait tile I landed ({K(I+1),V(I+1)}
// stay in flight); barrier; read V frags; release barrier; stage V(I+2);
// compute tile I.
#define ITER(I, CUR, NXT, DOK, DOV, WAITOP)                                \
    {                                                                      \
        if (DOK) KLOAD((I) + 1, NXT);                                      \
        WAITOP;                                                            \
        __builtin_amdgcn_s_barrier();                                      \
        VFRAGS(I);                                                         \
        LGW();                                                             \
        __builtin_amdgcn_s_barrier();                                      \
        if (DOV) STAGEV((I) + 2);                                          \
        COMPUTE((I), CUR);                                                 \
    }

// ---------- main attention kernel ----------
__global__ __launch_bounds__(256, 2) void attn_kernel(
    const float* __restrict__ Qg, const short* __restrict__ Kb,
    const short* __restrict__ Vtb, const float* __restrict__ biasg,
    const int* __restrict__ VL, float* __restrict__ Og)
{
    // V tile: 64 rows x 256B; row r holds v=2r (slots c<8) and v=2r+1 (c>=8),
    //         slot position p = c ^ (r&15)
    __shared__ __align__(16) short Vsh[2][64 * 128];   // 32768 B
    __shared__ __align__(16) float slab[8 * 1024];     // 32768 B (epilogue)
    __shared__ __align__(16) float biasSh[2][64];      //   512 B
    __shared__ float Lsum[4][32];                      //   512 B -> 66560 B total

    const int tid  = threadIdx.x;
    const int lane = tid & 63;
    const int w    = tid >> 6;    // wave 0..3
    const int pair = w >> 1;      // q-strip: rows [pair*32, pair*32+32)
    const int half = w & 1;       // key-half (S and PV k-range), wave-uniform
    const int l31  = lane & 31;
    const int hi   = lane >> 5;

    const int lin  = blockIdx.x;          // 0..511 ; XCD swizzle
    const int slot = lin >> 3;
    const int b    = (lin & 7) * 2 + (slot >> 5);
    const int q0   = (slot & 31) * BQ;

    const short* Kb_b = Kb  + (size_t)b * Kn * Dn;
    const short* Vt_b = Vtb + (size_t)b * DVn * Kn;
    const float* bias_b = biasg + b * Kn;

    const int kr  = half * 32 + l31;     // K row this lane feeds to S-MFMA
    // per-lane K pointer: row kr, d-chunk base hi*8 (kt*16 strides inside row)
    const short* kptr = Kb_b + (size_t)kr * Dn + hi * 8;

    // ---- V DMA source pointers ----
    const short* vsp[4]; int vdo[4];
#pragma unroll
    for (int i = 0; i < 4; ++i) {
        const int rv = w * 16 + i * 4 + (lane >> 4);       // V tile row 0..63
        const int cc = (lane & 15) ^ (rv & 15);            // source chunk
        const int vv = 2 * rv + (cc >> 3);
        vsp[i] = Vt_b + (size_t)vv * Kn + (cc & 7) * 8;
        vdo[i] = (w * 16 + i * 4) * 128;
    }

    // ---- Q fragments: frag layout [n=l31][k=kt*16+hi*8+j] ----
    bf16x8 qf[8];
    {
        const float* qrow = Qg + ((size_t)b * Qn + q0 + pair * 32 + l31) * Dn;
#pragma unroll
        for (int kt = 0; kt < 8; ++kt) {
            const float* p = qrow + kt * 16 + hi * 8;
            float4 x0 = *(const float4*)(p);
            float4 x1 = *(const float4*)(p + 4);
            bf16x8 f;
            f[0]=f2bf(x0.x); f[1]=f2bf(x0.y); f[2]=f2bf(x0.z); f[3]=f2bf(x0.w);
            f[4]=f2bf(x1.x); f[5]=f2bf(x1.y); f[6]=f2bf(x1.z); f[7]=f2bf(x1.w);
            qf[kt] = f;
        }
    }
    const int vlq = VL[b * Qn + q0 + pair * 32 + l31];

    f32x16 Oacc[4];   // v = nt*32 + l31, all 128 v; keys restricted to own half
#pragma unroll
    for (int nt = 0; nt < 4; ++nt)
#pragma unroll
        for (int j = 0; j < 16; ++j) Oacc[nt][j] = 0.f;
    float psum = 0.f;

    bf16x8 kfA[8], kfB[8];   // K frag ping-pong (tile parity)
    bf16x8 vfr[2][4];        // V fragments of current tile
    float4 bv[4];            // bias of current tile

    // prologue: V(0) DMA, K(0) regs, V(1) DMA.  iter0 then issues K(1) and
    // waits vmcnt(13) = {V(1)5, K(1)8} in flight, {V(0),K(0)} drained.
    STAGEV(0);
    KLOAD(0, kfA);
    STAGEV(1);

#pragma unroll 1
    for (int I2 = 0; I2 < 30; I2 += 2) {
        ITER(I2,     kfA, kfB, 1, 1, VMW13());
        ITER(I2 + 1, kfB, kfA, 1, 1, VMW13());
    }
    ITER(30, kfA, kfB, 1, 0, VMW13());   // loads K(31); no V(32)
    ITER(31, kfB, kfA, 0, 0, VMW0());    // drain

    // ---- epilogue: combine key-halves across wave pairs via LDS ----
    psum += __shfl_xor(psum, 32);
    if (lane < 32) Lsum[w][l31] = psum;
    __syncthreads();

    // write the half the PARTNER will store (literal Oacc indices; half is
    // wave-uniform so this is a scalar branch, not divergence)
    {
        float* dst0 = slab + ((pair * 2 + (1 - half)) * 2 + 0) * 1024;
        float* dst1 = slab + ((pair * 2 + (1 - half)) * 2 + 1) * 1024;
        if (half == 0) {
            DUMP_ACC(Oacc[2], dst0);
            DUMP_ACC(Oacc[3], dst1);
        } else {
            DUMP_ACC(Oacc[0], dst0);
            DUMP_ACC(Oacc[1], dst1);
        }
    }
    __syncthreads();

    float invl[16];
#pragma unroll
    for (int rq = 0; rq < 4; ++rq)
#pragma unroll
        for (int r = 0; r < 4; ++r) {
            const int ql = r + 8 * rq + 4 * hi;
            invl[rq*4+r] = 1.f / (Lsum[pair*2][ql] + Lsum[pair*2+1][ql]);
        }
    float* obase = Og + ((size_t)b * Qn + q0 + pair * 32) * DVn;
    {
        const float* src0 = slab + ((pair * 2 + half) * 2 + 0) * 1024;
        const float* src1 = slab + ((pair * 2 + half) * 2 + 1) * 1024;
        if (half == 0) {
            STORE_ACC(Oacc[0], src0, 0);
            STORE_ACC(Oacc[1], src1, 32);
        } else {
            STORE_ACC(Oacc[2], src0, 64);
            STORE_ACC(Oacc[3], src1, 96);
        }
    }
}

extern "C" void kernel_launch(void* const* d_in, const int* in_sizes, int n_in,
                              void* d_out, int out_size, void* d_ws, size_t ws_size,
                              hipStream_t stream) {
    const float* Qg = (const float*)d_in[0];
    const float* Kg = (const float*)d_in[1];
    const float* Vg = (const float*)d_in[2];
    const int*   VL = (const int*)d_in[3];
    float* Og = (float*)d_out;

    // ws: Kb bf16 (8MB) | Vtb bf16 (8MB) | bias2 f32 (128KB)
    char* ws = (char*)d_ws;
    short* Kb   = (short*)(ws);
    short* Vtb  = (short*)(ws + (size_t)Bn * Kn * Dn * 2);
    float* bias = (float*)(ws + (size_t)Bn * Kn * Dn * 4);

    prep_kv<<<dim3(1536), dim3(256), 0, stream>>>(Kg, Vg, Kb, Vtb, bias);
    attn_kernel<<<dim3(512), dim3(256), 0, stream>>>(Qg, Kb, Vtb, bias, VL, Og);
}

// Round 6
// 144.496 us; speedup vs baseline: 1.4822x; 1.4822x over previous
//
#include <hip/hip_runtime.h>

// B=16, Q=2048, K=2048, D=128, DV=128
// out[b,q,:] = softmax_k((q.k - 0.5||k||^2)/sqrt(192), mask k>=valid_len) @ V
// R14: varlen work-skipping. R8's attn core is the proven local optimum of
// this structure (64us; R9/R12 scheduling neutral, R10/R13 spilled). But
// valid_lens ~ U(1,2048) means ~half of all K-tiles are fully masked -> pure
// wasted work. prep now counting-sorts q-rows by valid_len per batch; each
// attn block takes 64 length-homogeneous rows (via perm) and iterates only
// ceil(max_vlq/64) tiles. Outputs scatter through the perm (bit-identical
// per-row math). Load balance: even batches ascending slots, odd batches
// descending, so the two blocks co-resident on a CU (XCD round-robin: slot c
// and c+32) sum to ~33 tiles. Wrong mapping assumption costs only balance.

#define Bn   16
#define Qn   2048
#define Kn   2048
#define Dn   128
#define DVn  128
#define BQ   64
#define BK   64

// (1/sqrt(192)) * log2(e) : softmax computed as 2^(qk*SC2 + bias2)
#define SC2 0.10411754f

typedef short bf16x4 __attribute__((ext_vector_type(4)));
typedef short bf16x8 __attribute__((ext_vector_type(8)));
typedef float f32x16 __attribute__((ext_vector_type(16)));

__device__ __forceinline__ short f2bf(float x) {   // RNE
    union { float f; unsigned u; } v; v.f = x;
    unsigned r = (v.u + 0x7fffu + ((v.u >> 16) & 1u)) >> 16;
    return (short)r;
}

typedef const __attribute__((address_space(1))) void* gas_t;
typedef __attribute__((address_space(3))) void* las_t;
__device__ __forceinline__ void gld16(const void* g, void* l) {
    __builtin_amdgcn_global_load_lds((gas_t)g, (las_t)l, 16, 0, 0);
}
__device__ __forceinline__ void gld4(const void* g, void* l) {
    __builtin_amdgcn_global_load_lds((gas_t)g, (las_t)l, 4, 0, 0);
}
__device__ __forceinline__ float exp2_raw(float a) {  // D = 2^S0
    float p;
    asm("v_exp_f32 %0, %1" : "=v"(p) : "v"(a));
    return p;
}

// ---------- preprocess: K/V convert (coalesced) + per-batch q-sort ----------
__global__ __launch_bounds__(256) void prep_kv(const float* __restrict__ Kg,
                                               const float* __restrict__ Vg,
                                               const int* __restrict__ VLg,
                                               short* __restrict__ Kb,
                                               short* __restrict__ Vtb,
                                               float* __restrict__ biasg,
                                               int* __restrict__ perm) {
    const int tid = threadIdx.x;
    if (blockIdx.x < 1024) {
        // ---- K path: 32 rows (b*Kn+row flat) per block, fully coalesced ----
        const int rowbase = blockIdx.x * 32;
        const float* src = Kg + (size_t)rowbase * Dn;
        short*       dst = Kb + (size_t)rowbase * Dn;
#pragma unroll
        for (int p = 0; p < 4; ++p) {
            const int idx = p * 1024 + tid * 4;     // flat float index
            float4 x = *(const float4*)(src + idx);
            bf16x4 h;
            h[0] = f2bf(x.x); h[1] = f2bf(x.y); h[2] = f2bf(x.z); h[3] = f2bf(x.w);
            *(bf16x4*)(dst + idx) = h;
            float ssq = x.x*x.x + x.y*x.y + x.z*x.z + x.w*x.w;
            ssq += __shfl_xor(ssq, 1);
            ssq += __shfl_xor(ssq, 2);
            ssq += __shfl_xor(ssq, 4);
            ssq += __shfl_xor(ssq, 8);
            ssq += __shfl_xor(ssq, 16);
            if ((tid & 31) == 0)
                biasg[rowbase + p * 8 + (tid >> 5)] = -0.5f * ssq * SC2;
        }
    } else if (blockIdx.x < 1536) {
        // ---- V path: transpose one [64 k][128 v] tile to plain V^T bf16 ----
        const int blk = blockIdx.x - 1024;
        const int b  = blk >> 5;
        const int k0 = (blk & 31) * 64;
        __shared__ short Ls[64 * 128];
        // phase 1: coalesced float4 row reads; XOR-swizzled LDS writes
#pragma unroll
        for (int p = 0; p < 8; ++p) {
            const int kk = p * 8 + (tid >> 5);      // tile row 0..63
            const int v0 = (tid & 31) * 4;
            float4 x = *(const float4*)(Vg + ((size_t)b * Kn + k0 + kk) * DVn + v0);
            bf16x4 h;
            h[0] = f2bf(x.x); h[1] = f2bf(x.y); h[2] = f2bf(x.z); h[3] = f2bf(x.w);
            const int vs = v0 ^ ((kk & 15) << 3);   // keeps 4-short alignment
            *(bf16x4*)&Ls[kk * 128 + vs] = h;
        }
        __syncthreads();
        // phase 2: column gather (32 scalar reads) + coalesced 64B stores
        const int v = tid >> 1;
        const int h = (tid & 1) * 32;
        short* dst = Vtb + ((size_t)b * DVn + v) * Kn + k0 + h;
#pragma unroll
        for (int j4 = 0; j4 < 4; ++j4) {
            bf16x8 o;
#pragma unroll
            for (int j = 0; j < 8; ++j) {
                const int kk = h + j4 * 8 + j;
                o[j] = Ls[kk * 128 + (v ^ ((kk & 15) << 3))];
            }
            *(bf16x8*)(dst + j4 * 8) = o;
        }
    } else {
        // ---- sort path: counting sort of 2048 q-rows by valid_len, batch b ----
        const int b = blockIdx.x - 1536;
        __shared__ int hist[2048];
        __shared__ int part[256];
        int vq[8];
#pragma unroll
        for (int i = 0; i < 8; ++i) hist[i * 256 + tid] = 0;
        __syncthreads();
#pragma unroll
        for (int i = 0; i < 8; ++i) {
            vq[i] = VLg[b * Qn + i * 256 + tid];    // 1..2048
            atomicAdd(&hist[vq[i] - 1], 1);
        }
        __syncthreads();
        // exclusive scan over 2048 bins (8 per thread + block scan)
        int lex[8]; int s = 0;
#pragma unroll
        for (int j = 0; j < 8; ++j) { lex[j] = s; s += hist[tid * 8 + j]; }
        part[tid] = s;
        __syncthreads();
        for (int off = 1; off < 256; off <<= 1) {
            int v = (tid >= off) ? part[tid - off] : 0;
            __syncthreads();
            part[tid] += v;
            __syncthreads();
        }
        const int excl = part[tid] - s;
#pragma unroll
        for (int j = 0; j < 8; ++j) hist[tid * 8 + j] = excl + lex[j];
        __syncthreads();
        // scatter: ascending positions by valid_len
#pragma unroll
        for (int i = 0; i < 8; ++i) {
            const int pos = atomicAdd(&hist[vq[i] - 1], 1);
            perm[b * Qn + pos] = i * 256 + tid;
        }
    }
}

// epilogue helpers with LITERAL accumulator indices (no runtime Oacc[] index)
#define DUMP_ACC(ACC, DST)                                            \
    {                                                                 \
        _Pragma("unroll")                                             \
        for (int reg = 0; reg < 16; ++reg) {                          \
            const int row = (reg & 3) + 8 * (reg >> 2) + 4 * hi;      \
            (DST)[row * 32 + l31] = (ACC)[reg];                       \
        }                                                             \
    }
#define STORE_ACC(ACC, SRC, COLBASE)                                  \
    {                                                                 \
        _Pragma("unroll")                                             \
        for (int reg = 0; reg < 16; ++reg) {                          \
            const int row = (reg & 3) + 8 * (reg >> 2) + 4 * hi;      \
            const float o = (ACC)[reg] + (SRC)[row * 32 + l31];       \
            Og_b[(size_t)permSh[pair * 32 + row] * DVn + (COLBASE) + l31] \
                = o * invl[reg];                                      \
        }                                                             \
    }

// ---------- main attention kernel (R8 core + perm gather + early exit) ----------
__global__ __launch_bounds__(256, 2) void attn_kernel(
    const float* __restrict__ Qg, const short* __restrict__ Kb,
    const short* __restrict__ Vtb, const float* __restrict__ biasg,
    const int* __restrict__ VL, const int* __restrict__ perm,
    float* __restrict__ Og)
{
    // K tile: 64 rows x 256B, chunk XOR by (row&15)
    // V tile: 64 rows x 256B; row r holds v=2r (slots c<8) and v=2r+1 (c>=8),
    //         slot position p = c ^ (r&15)
    __shared__ __align__(16) short Ksh[2][64 * 128];   // 32768 B (epilogue: float slab)
    __shared__ __align__(16) short Vsh[2][64 * 128];   // 32768 B
    __shared__ __align__(16) float biasSh[2][64];      //   512 B
    __shared__ float Lsum[4][32];                      //   512 B
    __shared__ int   permSh[64];                       //   256 B -> 66816 B total

    const int tid  = threadIdx.x;
    const int lane = tid & 63;
    const int w    = tid >> 6;    // wave 0..3
    const int pair = w >> 1;      // q-strip: rows [pair*32, pair*32+32)
    const int half = w & 1;       // key-half (S and PV k-range), wave-uniform
    const int l31  = lane & 31;
    const int hi   = lane >> 5;

    const int lin   = blockIdx.x;         // 0..511 ; XCD swizzle
    const int slot  = lin >> 3;
    const int b     = (lin & 7) * 2 + (slot >> 5);
    const int qslot = slot & 31;
    // even batches ascending, odd descending: the two blocks co-resident on a
    // CU (slot c and c+32 under XCD round-robin) then sum to ~33 tiles.
    const int lo    = ((b & 1) ? (31 - qslot) : qslot) * BQ;

    const short* Kb_b = Kb  + (size_t)b * Kn * Dn;
    const short* Vt_b = Vtb + (size_t)b * DVn * Kn;
    const float* bias_b = biasg + b * Kn;
    float* Og_b = Og + (size_t)b * Qn * DVn;

    if (tid < 64) permSh[tid] = perm[b * Qn + lo + tid];
    __syncthreads();

    // ---- DMA source pointers ----
    const short* ksp[4]; int kdo[4];
    const short* vsp[4]; int vdo[4];
#pragma unroll
    for (int i = 0; i < 4; ++i) {
        const int rl = w * 16 + i * 4 + (lane >> 4);       // K tile row 0..63
        const int ch = (lane & 15) ^ (rl & 15);
        ksp[i] = Kb_b + (size_t)rl * Dn + ch * 8;
        kdo[i] = (w * 16 + i * 4) * 128;
        const int rv = w * 16 + i * 4 + (lane >> 4);       // V tile row 0..63
        const int cc = (lane & 15) ^ (rv & 15);            // source chunk
        const int vv = 2 * rv + (cc >> 3);
        vsp[i] = Vt_b + (size_t)vv * Kn + (cc & 7) * 8;
        vdo[i] = (w * 16 + i * 4) * 128;
    }

    // ---- Q fragments (gathered via perm): [n=l31][k=kt*16+hi*8+j] ----
    const int qperm = permSh[pair * 32 + l31];
    bf16x8 qf[8];
    {
        const float* qrow = Qg + ((size_t)b * Qn + qperm) * Dn;
#pragma unroll
        for (int kt = 0; kt < 8; ++kt) {
            const float* p = qrow + kt * 16 + hi * 8;
            float4 x0 = *(const float4*)(p);
            float4 x1 = *(const float4*)(p + 4);
            bf16x8 f;
            f[0]=f2bf(x0.x); f[1]=f2bf(x0.y); f[2]=f2bf(x0.z); f[3]=f2bf(x0.w);
            f[4]=f2bf(x1.x); f[5]=f2bf(x1.y); f[6]=f2bf(x1.z); f[7]=f2bf(x1.w);
            qf[kt] = f;
        }
    }
    const int vlq  = VL[b * Qn + qperm];
    // rows sorted ascending within the job -> max valid_len is the last row
    const int KEnd = ((VL[b * Qn + permSh[63]] + BK - 1) >> 6) << 6;

    f32x16 Oacc[4];   // v = nt*32 + l31, all 128 v; keys restricted to own half
#pragma unroll
    for (int nt = 0; nt < 4; ++nt)
#pragma unroll
        for (int j = 0; j < 16; ++j) Oacc[nt][j] = 0.f;
    float psum = 0.f;

    // prologue: DMA tile 0 into buffer 0
#pragma unroll
    for (int i = 0; i < 4; ++i) {
        gld16(ksp[i], &Ksh[0][kdo[i]]);
        gld16(vsp[i], &Vsh[0][vdo[i]]);
    }
    if (w == 0) gld4(bias_b + lane, &biasSh[0][0]);

    for (int k0k = 0; k0k < KEnd; k0k += BK) {
        const int buf = (k0k >> 6) & 1;
        __syncthreads();   // drains vmcnt(0): tile ready; prev readers done

        if (k0k + BK < KEnd) {
            const int nk = k0k + BK;
#pragma unroll
            for (int i = 0; i < 4; ++i) {
                gld16(ksp[i] + (size_t)nk * Dn, &Ksh[buf ^ 1][kdo[i]]);
                gld16(vsp[i] + nk,              &Vsh[buf ^ 1][vdo[i]]);
            }
            if (w == 0) gld4(bias_b + nk + lane, &biasSh[buf ^ 1][0]);
        }

        float4 bv[4];
#pragma unroll
        for (int rq = 0; rq < 4; ++rq)
            bv[rq] = *(const float4*)&biasSh[buf][half * 32 + rq * 8 + hi * 4];

        // ---- S^T = K_half . Q^T : one 32x32 tile per wave (8 MFMA) ----
        const short* kbuf = Ksh[buf];
        const int kr = half * 32 + l31;
        f32x16 Sv;
#pragma unroll
        for (int j = 0; j < 16; ++j) Sv[j] = 0.f;
#pragma unroll
        for (int kt = 0; kt < 8; ++kt) {
            bf16x8 kf = *(const bf16x8*)&kbuf[kr * 128 + (((kt*2 + hi) ^ (kr & 15)) * 8)];
            Sv = __builtin_amdgcn_mfma_f32_32x32x16_bf16(kf, qf[kt], Sv, 0, 0, 0);
        }

        // ---- softmax in exp2 domain (results back into Sv) ----
#pragma unroll
        for (int rq = 0; rq < 4; ++rq) {
#pragma unroll
            for (int r = 0; r < 4; ++r) {
                const int reg = rq * 4 + r;
                const int keyg = k0k + half * 32 + rq * 8 + hi * 4 + r;
                float a = fmaf(Sv[reg], SC2, bv[rq][r]);
                a = (keyg < vlq) ? a : -200.0f;
                const float p = exp2_raw(a);
                psum += p;
                Sv[reg] = p;
            }
        }

        // ---- PV: C-layout -> A-layout via lane^32 exchange; 8 MFMA ----
        const short* vbuf = Vsh[buf];
#pragma unroll
        for (int kt = 0; kt < 2; ++kt) {
            unsigned kAx = __builtin_amdgcn_perm(__float_as_uint(Sv[(2*kt)*4+1]),
                                                 __float_as_uint(Sv[(2*kt)*4+0]), 0x07060302u);
            unsigned kAy = __builtin_amdgcn_perm(__float_as_uint(Sv[(2*kt)*4+3]),
                                                 __float_as_uint(Sv[(2*kt)*4+2]), 0x07060302u);
            unsigned kBx = __builtin_amdgcn_perm(__float_as_uint(Sv[(2*kt+1)*4+1]),
                                                 __float_as_uint(Sv[(2*kt+1)*4+0]), 0x07060302u);
            unsigned kBy = __builtin_amdgcn_perm(__float_as_uint(Sv[(2*kt+1)*4+3]),
                                                 __float_as_uint(Sv[(2*kt+1)*4+2]), 0x07060302u);
            const unsigned sx = hi ? kAx : kBx;
            const unsigned sy = hi ? kAy : kBy;
            const unsigned rx = __shfl_xor(sx, 32);
            const unsigned ry = __shfl_xor(sy, 32);
            uint4 au;
            au.x = hi ? rx : kAx;
            au.y = hi ? ry : kAy;
            au.z = hi ? kBx : rx;
            au.w = hi ? kBy : ry;
            const bf16x8 af = __builtin_bit_cast(bf16x8, au);
            const int kc = half * 4 + kt * 2 + hi;   // key-chunk within 64-key tile
#pragma unroll
            for (int nt = 0; nt < 4; ++nt) {
                const int v  = nt * 32 + l31;
                const int r  = v >> 1;
                const int p  = ((v & 1) * 8 + kc) ^ (r & 15);
                bf16x8 vf = *(const bf16x8*)&vbuf[r * 128 + p * 8];
                Oacc[nt] = __builtin_amdgcn_mfma_f32_32x32x16_bf16(af, vf, Oacc[nt], 0, 0, 0);
            }
        }
    }

    // ---- epilogue: combine key-halves across wave pairs via LDS ----
    psum += __shfl_xor(psum, 32);
    if (lane < 32) Lsum[w][l31] = psum;
    __syncthreads();   // all waves done reading Ksh/Vsh -> safe to reuse Ksh

    float* slab = (float*)&Ksh[0][0];
    // write the half the PARTNER will store (literal Oacc indices; half is
    // wave-uniform so this is a scalar branch, not divergence)
    {
        float* dst0 = slab + ((pair * 2 + (1 - half)) * 2 + 0) * 1024;
        float* dst1 = slab + ((pair * 2 + (1 - half)) * 2 + 1) * 1024;
        if (half == 0) {
            DUMP_ACC(Oacc[2], dst0);
            DUMP_ACC(Oacc[3], dst1);
        } else {
            DUMP_ACC(Oacc[0], dst0);
            DUMP_ACC(Oacc[1], dst1);
        }
    }
    __syncthreads();

    float invl[16];
#pragma unroll
    for (int rq = 0; rq < 4; ++rq)
#pragma unroll
        for (int r = 0; r < 4; ++r) {
            const int ql = r + 8 * rq + 4 * hi;
            invl[rq*4+r] = 1.f / (Lsum[pair*2][ql] + Lsum[pair*2+1][ql]);
        }
    {
        const float* src0 = slab + ((pair * 2 + half) * 2 + 0) * 1024;
        const float* src1 = slab + ((pair * 2 + half) * 2 + 1) * 1024;
        if (half == 0) {
            STORE_ACC(Oacc[0], src0, 0);
            STORE_ACC(Oacc[1], src1, 32);
        } else {
            STORE_ACC(Oacc[2], src0, 64);
            STORE_ACC(Oacc[3], src1, 96);
        }
    }
}

extern "C" void kernel_launch(void* const* d_in, const int* in_sizes, int n_in,
                              void* d_out, int out_size, void* d_ws, size_t ws_size,
                              hipStream_t stream) {
    const float* Qg = (const float*)d_in[0];
    const float* Kg = (const float*)d_in[1];
    const float* Vg = (const float*)d_in[2];
    const int*   VL = (const int*)d_in[3];
    float* Og = (float*)d_out;
    (void)ws_size;

    // ws: Kb bf16 (8MB) | Vtb bf16 (8MB) | bias f32 (128KB) | perm int (128KB)
    char* ws = (char*)d_ws;
    short* Kb   = (short*)(ws);
    short* Vtb  = (short*)(ws + (size_t)Bn * Kn * Dn * 2);
    float* bias = (float*)(ws + (size_t)Bn * Kn * Dn * 4);
    int*   perm = (int*)  (ws + (size_t)Bn * Kn * Dn * 4 + 131072);

    prep_kv<<<dim3(1552), dim3(256), 0, stream>>>(Kg, Vg, VL, Kb, Vtb, bias, perm);
    attn_kernel<<<dim3(512), dim3(256), 0, stream>>>(Qg, Kb, Vtb, bias, VL, perm, Og);
}